// Round 1
// baseline (95.117 us; speedup 1.0000x reference)
//
#include <hip/hip_runtime.h>

// out[i,j] = sum_k relu(a@feats^T)[i,k] * ((b@feats^T)[j,k] <= 0)
// Na=Nb=1024, D=512, K=256.
//
// Kernel A: X = [a;b] (2048x512) @ feats^T (512x256) with fused epilogue:
//   rows <1024  -> p  = relu(dot)
//   rows >=1024 -> msk = (dot <= 0) ? 1 : 0
// Kernel B: out (1024x1024) = p (1024x256) @ msk^T (1024x256 row-major, contract k)

#define BM 64
#define BN 64
#define BK 32
#define PAD 4   // 64+4=68 floats/row: 272 B = 17*16 B -> float4-aligned, stride%32=4 banks

__global__ __launch_bounds__(256) void gemm_af_kernel(
    const float* __restrict__ a, const float* __restrict__ b,
    const float* __restrict__ feats, float* __restrict__ p, float* __restrict__ msk)
{
    // grid = (2048/BM) * (256/BN) = 32*4 = 128 blocks
    const int num_n = 256 / BN;             // 4
    const int bm = blockIdx.x / num_n;
    const int bn = blockIdx.x % num_n;
    const int m0 = bm * BM;                 // 0..2047 (combined a;b rows)
    const int n0 = bn * BN;

    const float* X;
    float* Out;
    bool is_a;
    if (m0 < 1024) { X = a + (size_t)m0 * 512; Out = p   + (size_t)m0        * 256; is_a = true;  }
    else           { X = b + (size_t)(m0 - 1024) * 512; Out = msk + (size_t)(m0 - 1024) * 256; is_a = false; }

    __shared__ float Xs[BK][BM + PAD];
    __shared__ float Fs[BK][BN + PAD];

    const int tid = threadIdx.x;
    const int tm = tid / 16;   // 0..15
    const int tn = tid % 16;   // 0..15

    float acc[4][4];
    #pragma unroll
    for (int i = 0; i < 4; i++)
        #pragma unroll
        for (int j = 0; j < 4; j++) acc[i][j] = 0.f;

    for (int k0 = 0; k0 < 512; k0 += BK) {
        // Load X tile 64x32 (coalesced float4), store transposed.
        #pragma unroll
        for (int r = 0; r < 2; r++) {
            int idx = tid + r * 256;      // 0..511
            int lm  = idx >> 3;           // 0..63
            int lk  = (idx & 7) * 4;      // 0..28
            float4 v = *(const float4*)(X + lm * 512 + k0 + lk);
            Xs[lk + 0][lm] = v.x; Xs[lk + 1][lm] = v.y;
            Xs[lk + 2][lm] = v.z; Xs[lk + 3][lm] = v.w;
        }
        // Load feats tile 64x32 (rows n0..n0+63), transposed.
        #pragma unroll
        for (int r = 0; r < 2; r++) {
            int idx = tid + r * 256;
            int ln  = idx >> 3;
            int lk  = (idx & 7) * 4;
            float4 v = *(const float4*)(feats + (size_t)(n0 + ln) * 512 + k0 + lk);
            Fs[lk + 0][ln] = v.x; Fs[lk + 1][ln] = v.y;
            Fs[lk + 2][ln] = v.z; Fs[lk + 3][ln] = v.w;
        }
        __syncthreads();

        #pragma unroll
        for (int kk = 0; kk < BK; kk++) {
            float xv[4], fv[4];
            #pragma unroll
            for (int i = 0; i < 4; i++) xv[i] = Xs[kk][tm * 4 + i];
            #pragma unroll
            for (int j = 0; j < 4; j++) fv[j] = Fs[kk][tn * 4 + j];
            #pragma unroll
            for (int i = 0; i < 4; i++)
                #pragma unroll
                for (int j = 0; j < 4; j++)
                    acc[i][j] += xv[i] * fv[j];
        }
        __syncthreads();
    }

    #pragma unroll
    for (int i = 0; i < 4; i++) {
        int row = tm * 4 + i;
        #pragma unroll
        for (int j = 0; j < 4; j++) {
            int col = n0 + tn * 4 + j;
            float v = acc[i][j];
            float o = is_a ? (v > 0.f ? v : 0.f) : (v <= 0.f ? 1.f : 0.f);
            Out[row * 256 + col] = o;
        }
    }
}

__global__ __launch_bounds__(256) void gemm_pm_kernel(
    const float* __restrict__ p, const float* __restrict__ msk,
    float* __restrict__ out)
{
    // grid = (1024/64)^2 = 256 blocks
    const int bi = blockIdx.x / 16;
    const int bj = blockIdx.x % 16;
    const int i0 = bi * BM;
    const int j0 = bj * BN;

    __shared__ float Ps[BK][BM + PAD];
    __shared__ float Ms[BK][BN + PAD];

    const int tid = threadIdx.x;
    const int tm = tid / 16;
    const int tn = tid % 16;

    float acc[4][4];
    #pragma unroll
    for (int i = 0; i < 4; i++)
        #pragma unroll
        for (int j = 0; j < 4; j++) acc[i][j] = 0.f;

    for (int k0 = 0; k0 < 256; k0 += BK) {
        #pragma unroll
        for (int r = 0; r < 2; r++) {
            int idx = tid + r * 256;
            int li  = idx >> 3;
            int lk  = (idx & 7) * 4;
            float4 v = *(const float4*)(p + (size_t)(i0 + li) * 256 + k0 + lk);
            Ps[lk + 0][li] = v.x; Ps[lk + 1][li] = v.y;
            Ps[lk + 2][li] = v.z; Ps[lk + 3][li] = v.w;
        }
        #pragma unroll
        for (int r = 0; r < 2; r++) {
            int idx = tid + r * 256;
            int lj  = idx >> 3;
            int lk  = (idx & 7) * 4;
            float4 v = *(const float4*)(msk + (size_t)(j0 + lj) * 256 + k0 + lk);
            Ms[lk + 0][lj] = v.x; Ms[lk + 1][lj] = v.y;
            Ms[lk + 2][lj] = v.z; Ms[lk + 3][lj] = v.w;
        }
        __syncthreads();

        #pragma unroll
        for (int kk = 0; kk < BK; kk++) {
            float pv[4], mv[4];
            #pragma unroll
            for (int i = 0; i < 4; i++) pv[i] = Ps[kk][tm * 4 + i];
            #pragma unroll
            for (int j = 0; j < 4; j++) mv[j] = Ms[kk][tn * 4 + j];
            #pragma unroll
            for (int i = 0; i < 4; i++)
                #pragma unroll
                for (int j = 0; j < 4; j++)
                    acc[i][j] += pv[i] * mv[j];
        }
        __syncthreads();
    }

    #pragma unroll
    for (int i = 0; i < 4; i++) {
        int row = i0 + tm * 4 + i;
        #pragma unroll
        for (int j = 0; j < 4; j++) {
            int col = j0 + tn * 4 + j;
            out[(size_t)row * 1024 + col] = acc[i][j];
        }
    }
}

extern "C" void kernel_launch(void* const* d_in, const int* in_sizes, int n_in,
                              void* d_out, int out_size, void* d_ws, size_t ws_size,
                              hipStream_t stream) {
    const float* a     = (const float*)d_in[0];   // 1024x512
    const float* b     = (const float*)d_in[1];   // 1024x512
    const float* feats = (const float*)d_in[2];   // 256x512
    float* out = (float*)d_out;                   // 1024x1024
    float* p   = (float*)d_ws;                    // 1024x256
    float* msk = p + 1024 * 256;                  // 1024x256

    gemm_af_kernel<<<128, 256, 0, stream>>>(a, b, feats, p, msk);
    gemm_pm_kernel<<<256, 256, 0, stream>>>(p, msk, out);
}

// Round 2
// 81.423 us; speedup vs baseline: 1.1682x; 1.1682x over previous
//
#include <hip/hip_runtime.h>
#include <hip/hip_bf16.h>

// out[i,j] = sum_k relu(a@feats^T)[i,k] * ((b@feats^T)[j,k] <= 0)
// Na=Nb=1024, D=512, K=256.
//
// stage1  (f32 vector, K-split 4): part[ks] = X[tile] @ feats^T  (X=[a;b], 2048x512)
//         512 blocks (2/CU) instead of round-1's 128 (0.5/CU).
// epilogue: sum partials; rows<1024 -> p=relu as bf16; rows>=1024 -> msk=(v<=0) as bf16.
//           Mask sign decision stays full-f32 (bf16 GEMM here would widen the flip
//           window ~10x and risk > threshold errors; p bf16 rounding is benign).
// gemm2   (MFMA bf16 16x16x32): out = p @ msk^T. Both operands [N][K] row-major ->
//         A/B frags are 8 contiguous bf16 per lane (verified gemm_bt pattern).

typedef short bf16x8 __attribute__((ext_vector_type(8)));
typedef float f32x4  __attribute__((ext_vector_type(4)));

#define BM 64
#define BN 64
#define BK 32
#define PAD 4   // 68-float stride: 272 B, float4-aligned

__global__ __launch_bounds__(256) void stage1_kernel(
    const float* __restrict__ a, const float* __restrict__ b,
    const float* __restrict__ feats, float* __restrict__ part)
{
    // grid = 128 tiles (32 m x 4 n) * 4 ksplits = 512 blocks
    const int tile = blockIdx.x >> 2;
    const int ks   = blockIdx.x & 3;
    const int bm = tile >> 2;            // 0..31
    const int bn = tile & 3;             // 0..3
    const int m0 = bm * BM;              // 0..2047 combined [a;b] row
    const int n0 = bn * BN;

    const float* X = (m0 < 1024) ? (a + (size_t)m0 * 512)
                                 : (b + (size_t)(m0 - 1024) * 512);
    float* Out = part + (size_t)ks * 2048 * 256 + (size_t)m0 * 256;

    __shared__ float Xs[BK][BM + PAD];
    __shared__ float Fs[BK][BN + PAD];

    const int tid = threadIdx.x;
    const int tm = tid >> 4;   // 0..15
    const int tn = tid & 15;   // 0..15

    float acc[4][4];
    #pragma unroll
    for (int i = 0; i < 4; i++)
        #pragma unroll
        for (int j = 0; j < 4; j++) acc[i][j] = 0.f;

    const int kbase = ks * 128;          // this block's K range: [kbase, kbase+128)
    for (int kt = 0; kt < 4; kt++) {
        const int k0 = kbase + kt * BK;
        #pragma unroll
        for (int r = 0; r < 2; r++) {
            int idx = tid + r * 256;      // 0..511
            int lm  = idx >> 3;           // 0..63
            int lk  = (idx & 7) * 4;      // 0..28
            float4 v = *(const float4*)(X + (size_t)lm * 512 + k0 + lk);
            Xs[lk + 0][lm] = v.x; Xs[lk + 1][lm] = v.y;
            Xs[lk + 2][lm] = v.z; Xs[lk + 3][lm] = v.w;
        }
        #pragma unroll
        for (int r = 0; r < 2; r++) {
            int idx = tid + r * 256;
            int ln  = idx >> 3;
            int lk  = (idx & 7) * 4;
            float4 v = *(const float4*)(feats + (size_t)(n0 + ln) * 512 + k0 + lk);
            Fs[lk + 0][ln] = v.x; Fs[lk + 1][ln] = v.y;
            Fs[lk + 2][ln] = v.z; Fs[lk + 3][ln] = v.w;
        }
        __syncthreads();

        #pragma unroll
        for (int kk = 0; kk < BK; kk++) {
            float xv[4], fv[4];
            #pragma unroll
            for (int i = 0; i < 4; i++) xv[i] = Xs[kk][tm * 4 + i];
            #pragma unroll
            for (int j = 0; j < 4; j++) fv[j] = Fs[kk][tn * 4 + j];
            #pragma unroll
            for (int i = 0; i < 4; i++)
                #pragma unroll
                for (int j = 0; j < 4; j++)
                    acc[i][j] += xv[i] * fv[j];
        }
        __syncthreads();
    }

    #pragma unroll
    for (int i = 0; i < 4; i++) {
        int row = tm * 4 + i;
        #pragma unroll
        for (int j = 0; j < 4; j++) {
            int col = n0 + tn * 4 + j;
            Out[row * 256 + col] = acc[i][j];
        }
    }
}

__global__ __launch_bounds__(256) void epilogue_kernel(
    const float* __restrict__ part,
    __hip_bfloat16* __restrict__ pbf, __hip_bfloat16* __restrict__ mbf)
{
    // 2048*256 elements, 4 per thread -> 131072 threads = 512 blocks
    const int g = blockIdx.x * 256 + threadIdx.x;
    const int row = g >> 6;              // 0..2047
    const int c4  = (g & 63) * 4;        // 0..252

    const float* base = part + (size_t)row * 256 + c4;
    float4 s = *(const float4*)base;
    #pragma unroll
    for (int sdx = 1; sdx < 4; sdx++) {
        float4 v = *(const float4*)(base + (size_t)sdx * 2048 * 256);
        s.x += v.x; s.y += v.y; s.z += v.z; s.w += v.w;
    }

    if (row < 1024) {
        __hip_bfloat16* o = pbf + (size_t)row * 256 + c4;
        o[0] = __float2bfloat16(fmaxf(s.x, 0.f));
        o[1] = __float2bfloat16(fmaxf(s.y, 0.f));
        o[2] = __float2bfloat16(fmaxf(s.z, 0.f));
        o[3] = __float2bfloat16(fmaxf(s.w, 0.f));
    } else {
        __hip_bfloat16* o = mbf + (size_t)(row - 1024) * 256 + c4;
        o[0] = __float2bfloat16(s.x <= 0.f ? 1.f : 0.f);
        o[1] = __float2bfloat16(s.y <= 0.f ? 1.f : 0.f);
        o[2] = __float2bfloat16(s.z <= 0.f ? 1.f : 0.f);
        o[3] = __float2bfloat16(s.w <= 0.f ? 1.f : 0.f);
    }
}

__global__ __launch_bounds__(256) void gemm2_kernel(
    const __hip_bfloat16* __restrict__ p, const __hip_bfloat16* __restrict__ m,
    float* __restrict__ out)
{
    // out (1024x1024) = p (1024x256) @ m^T (m is 1024x256 row-major, contract k)
    // Block tile 32(i) x 64(j); 4 waves in 2x2; wave tile 16x32 (1 A-frag, 2 B-frags).
    // grid = 32 * 16 = 512 blocks.
    const int bi = blockIdx.x >> 4;      // 0..31
    const int bj = blockIdx.x & 15;      // 0..15
    const int i0 = bi * 32;
    const int j0 = bj * 64;

    const int tid  = threadIdx.x;
    const int w    = tid >> 6;           // 0..3
    const int lane = tid & 63;
    const int wi = w >> 1;               // 0..1
    const int wj = w & 1;                // 0..1

    const int l15 = lane & 15;
    const int q   = lane >> 4;           // 0..3

    const int arow  = i0 + wi * 16 + l15;       // A: row = lane&15
    const int jbase = j0 + wj * 32;
    const int brow0 = jbase + l15;              // B frag 0
    const int brow1 = brow0 + 16;               // B frag 1

    const short* ps = (const short*)p;
    const short* ms = (const short*)m;

    f32x4 acc0 = {0.f, 0.f, 0.f, 0.f};
    f32x4 acc1 = {0.f, 0.f, 0.f, 0.f};

    #pragma unroll
    for (int k0 = 0; k0 < 256; k0 += 32) {
        const int ko = k0 + q * 8;               // k = (lane>>4)*8 + j
        bf16x8 av = *(const bf16x8*)(ps + (size_t)arow  * 256 + ko);
        bf16x8 b0 = *(const bf16x8*)(ms + (size_t)brow0 * 256 + ko);
        bf16x8 b1 = *(const bf16x8*)(ms + (size_t)brow1 * 256 + ko);
        acc0 = __builtin_amdgcn_mfma_f32_16x16x32_bf16(av, b0, acc0, 0, 0, 0);
        acc1 = __builtin_amdgcn_mfma_f32_16x16x32_bf16(av, b1, acc1, 0, 0, 0);
    }

    // C/D layout: col = lane&15, row = (lane>>4)*4 + reg
    const int orow = i0 + wi * 16 + q * 4;
    const int ocol = jbase + l15;
    #pragma unroll
    for (int r = 0; r < 4; r++) {
        out[(size_t)(orow + r) * 1024 + ocol]      = acc0[r];
        out[(size_t)(orow + r) * 1024 + ocol + 16] = acc1[r];
    }
}

extern "C" void kernel_launch(void* const* d_in, const int* in_sizes, int n_in,
                              void* d_out, int out_size, void* d_ws, size_t ws_size,
                              hipStream_t stream) {
    const float* a     = (const float*)d_in[0];   // 1024x512
    const float* b     = (const float*)d_in[1];   // 1024x512
    const float* feats = (const float*)d_in[2];   // 256x512
    float* out = (float*)d_out;                   // 1024x1024

    float* part = (float*)d_ws;                                   // 4 * 2048*256 f32 = 8 MB
    __hip_bfloat16* pbf = (__hip_bfloat16*)((char*)d_ws + (size_t)8 * 1024 * 1024);
    __hip_bfloat16* mbf = pbf + 1024 * 256;                       // 512 KB each

    stage1_kernel  <<<512, 256, 0, stream>>>(a, b, feats, part);
    epilogue_kernel<<<512, 256, 0, stream>>>(part, pbf, mbf);
    gemm2_kernel   <<<512, 256, 0, stream>>>(pbf, mbf, out);
}